// Round 5
// baseline (350.746 us; speedup 1.0000x reference)
//
#include <hip/hip_runtime.h>
#include <hip/hip_cooperative_groups.h>

namespace cg = cooperative_groups;

// NGP multiresolution hash-grid interpolation encoding.
// B=262144 points, DIM=3, L=16 levels, T=19 (2^19 entries/level), F=2.
//
// R9: single cooperative kernel + dense re-indexed tables for levels 3-6.
// Ledger: fine hash level = 1.57M L2 req served by ONE XCD (~59us XCD-time);
// 13 levels / 8 XCDs = 92-96us makespan (R6/R8). Coarse-LDS only nets ~6us
// (levels 0-2 were partially L1-served already). Dispatch boundary ~5-7us.
// Moves:
//  - Phase A: build dense[l][ix+E*iy+E^2*iz] = tables[l][hash] for l=3..6
//    (0.26M paired loads). Gather then uses ONE unaligned 16B load per
//    corner pair -> 4 req/pt (vs avg 6) and 0.29-2.2MB L2 footprints.
//  - Phase C: coarse LDS z-slabs (R8) + dense levels 3-6 + hash levels 7-15,
//    per-XCD weighted chunk ranges (41:60 dense:hash) with a per-XCD atomic
//    work counter (level-major order preserved, self-balancing).
//  - Phase E: transpose fused (reuses the 39.4KB LDS as a 16x257 tile).
//  - grid.sync() between phases; coop grid sized by occupancy query;
//    fallback to the proven R8 path on any failure.

#define NB 262144
#define NL 16
#define TSIZE (1u << 19)
#define TMASK ((1u << 19) - 1u)
#define P1 2654435761u
#define P2 805459861u

#define NCL 3
#define CPTS 8192
#define CLDS_ENT (17 * 17 * 17)        // 4913 vf2 = 39304 B

// dense levels 3..6: E = res+1, offsets in vf2 units (8B), 8-aligned
#define E3 33
#define E4 41
#define E5 51
#define E6 65
#define DOFF3 0
#define DOFF4 35944
#define DOFF5 104872
#define DOFF6 237528
#define DENSE_TOTAL 512160             // vf2 entries (4,097,280 B)

// phase-A fill units (even-x pairs): HE*E*E per level
#define FC1 18513                      // end of E3
#define FC2 53814                      // end of E4
#define FC3 121440                     // end of E5
#define FTOTAL 260865                  // end of E6

// fine chunks: 13 levels x 512 chunks of 512 points, level-major
#define FINE_TOTAL 6656

typedef float vf2 __attribute__((ext_vector_type(2)));
typedef float vf4 __attribute__((ext_vector_type(4)));

__constant__ float RES_C[NL] = {16.f, 20.f, 25.f, 32.f, 40.f, 50.f, 64.f, 80.f,
                                101.f, 128.f, 161.f, 203.f, 256.f, 322.f, 406.f, 512.f};

// weighted per-XCD fine-chunk splits (dense chunk = 41, hash chunk = 60)
__constant__ int XSPLIT[9] = {0, 1099, 2150, 2901, 3652, 4403, 5154, 5905, 6656};

__device__ __forceinline__ void ngp_point_level(
    float px, float py, float pz, int l, const float* __restrict__ tables,
    float& o0, float& o1) {
  const float res = RES_C[l];
  const float sx = px * res, sy = py * res, sz = pz * res;
  const float fx = floorf(sx), fy = floorf(sy), fz = floorf(sz);
  const unsigned ix = (unsigned)fx, iy = (unsigned)fy, iz = (unsigned)fz;

  const unsigned hy0 = iy * P1, hy1 = hy0 + P1;
  const unsigned hz0 = iz * P2, hz1 = hz0 + P2;

  const float wx0 = 1.0f - fabsf(sx - fx);
  const float wx1 = 1.0f - fabsf(sx - (fx + 1.0f));
  const float wy0 = 1.0f - fabsf(sy - fy);
  const float wy1 = 1.0f - fabsf(sy - (fy + 1.0f));
  const float wz0 = 1.0f - fabsf(sz - fz);
  const float wz1 = 1.0f - fabsf(sz - (fz + 1.0f));

  const vf2* __restrict__ tbl2 = (const vf2*)tables + (size_t)l * TSIZE;
  const vf4* __restrict__ tbl4 = (const vf4*)tables + (size_t)l * (TSIZE / 2);

  unsigned hyz[4];
  hyz[0] = hy0 ^ hz0;
  hyz[1] = hy1 ^ hz0;
  hyz[2] = hy0 ^ hz1;
  hyz[3] = hy1 ^ hz1;

  vf2 g[8];  // g[v], v = xbit + 2*ybit + 4*zbit
  if ((ix & 1u) == 0u) {
#pragma unroll
    for (int p = 0; p < 4; ++p) {
      const unsigned i0 = (ix ^ hyz[p]) & TMASK;
      const vf4 q = tbl4[i0 >> 1];
      vf2 lo; lo.x = q.x; lo.y = q.y;
      vf2 hi; hi.x = q.z; hi.y = q.w;
      const bool x0_is_lo = (i0 & 1u) == 0u;
      g[2 * p + 0] = x0_is_lo ? lo : hi;
      g[2 * p + 1] = x0_is_lo ? hi : lo;
    }
  } else {
#pragma unroll
    for (int p = 0; p < 4; ++p) {
      const unsigned i0 = (ix ^ hyz[p]) & TMASK;
      const unsigned i1 = ((ix + 1u) ^ hyz[p]) & TMASK;
      g[2 * p + 0] = tbl2[i0];
      g[2 * p + 1] = tbl2[i1];
    }
  }

  o0 = 0.0f; o1 = 0.0f;
#pragma unroll
  for (int v = 0; v < 8; ++v) {
    const float w = ((v & 1) ? wx1 : wx0) * ((v & 2) ? wy1 : wy0) * ((v & 4) ? wz1 : wz0);
    o0 = fmaf(w, g[v].x, o0);
    o1 = fmaf(w, g[v].y, o1);
  }
}

// ---- dense-gather point (levels 3-6): coordinate-indexed table ----
template <int E, int DOFF_>
__device__ __forceinline__ void dense_point(
    float px, float py, float pz, float res, const vf2* __restrict__ dense,
    float& o0, float& o1) {
  const float sx = px * res, sy = py * res, sz = pz * res;
  const float fx = floorf(sx), fy = floorf(sy), fz = floorf(sz);
  const int ix = (int)fx, iy = (int)fy, iz = (int)fz;

  const float wx0 = 1.0f - fabsf(sx - fx);
  const float wx1 = 1.0f - fabsf(sx - (fx + 1.0f));
  const float wy0 = 1.0f - fabsf(sy - fy);
  const float wy1 = 1.0f - fabsf(sy - (fy + 1.0f));
  const float wz0 = 1.0f - fabsf(sz - fz);
  const float wz1 = 1.0f - fabsf(sz - (fz + 1.0f));

  const vf2* __restrict__ dp = dense + DOFF_ + ix + E * iy + E * E * iz;

  vf2 g[8];
#pragma unroll
  for (int p = 0; p < 4; ++p) {
    const int row = ((p & 1) ? E : 0) + ((p & 2) ? E * E : 0);
    vf4 q;  // one unaligned 16B load serves corners ix and ix+1
    __builtin_memcpy(&q, (const void*)(dp + row), 16);
    g[2 * p + 0].x = q.x; g[2 * p + 0].y = q.y;
    g[2 * p + 1].x = q.z; g[2 * p + 1].y = q.w;
  }

  o0 = 0.0f; o1 = 0.0f;
#pragma unroll
  for (int v = 0; v < 8; ++v) {
    const float w = ((v & 1) ? wx1 : wx0) * ((v & 2) ? wy1 : wy0) * ((v & 4) ? wz1 : wz0);
    o0 = fmaf(w, g[v].x, o0);
    o1 = fmaf(w, g[v].y, o1);
  }
}

// ---- coarse z-slab (levels 0-2), 512 threads, callable repeatedly ----
template <int E, int PLANES>
__device__ __forceinline__ void coarse_slab(
    const int lvl, const int zbase, const int c_lo, const int c_hi,
    const int cchunk, const float* __restrict__ x,
    const float* __restrict__ tables, vf2* __restrict__ ws,
    vf2* __restrict__ cache) {
  const int tid = threadIdx.x;
  const vf4* __restrict__ tbl4 = (const vf4*)tables + (size_t)lvl * (TSIZE / 2);

  constexpr int HE = (E + 1) / 2;
  constexpr int U = HE * E * PLANES;

  __syncthreads();  // protect cache from a previous item's readers
  for (int u = tid; u < U; u += 512) {
    const int zp = u / (HE * E);
    const int rem = u - zp * (HE * E);
    const int iy = rem / HE;
    const int ixh = rem - iy * HE;
    const unsigned ix = 2u * (unsigned)ixh;
    const unsigned iz = (unsigned)(zbase + zp);
    const unsigned h0 = (ix ^ ((unsigned)iy * P1) ^ (iz * P2)) & TMASK;
    const vf4 q = tbl4[h0 >> 1];
    vf2 lo; lo.x = q.x; lo.y = q.y;
    vf2 hi; hi.x = q.z; hi.y = q.w;
    const bool x0_is_lo = (h0 & 1u) == 0u;
    const int d0 = (int)ix + E * iy + E * E * zp;
    cache[d0] = x0_is_lo ? lo : hi;
    if ((int)ix + 1 < E) cache[d0 + 1] = x0_is_lo ? hi : lo;
  }
  __syncthreads();

  const float res = RES_C[lvl];
  const int base = cchunk * CPTS;
#pragma unroll
  for (int k = 0; k < CPTS / 512; ++k) {
    const int b = base + k * 512 + tid;
    const float px = x[b * 3 + 0];
    const float py = x[b * 3 + 1];
    const float pz = x[b * 3 + 2];

    const float sx = px * res, sy = py * res, sz = pz * res;
    const float fx = floorf(sx), fy = floorf(sy), fz = floorf(sz);
    const int ix = (int)fx, iy = (int)fy, iz = (int)fz;

    if (iz >= c_lo && iz <= c_hi) {
      const float wx0 = 1.0f - fabsf(sx - fx);
      const float wx1 = 1.0f - fabsf(sx - (fx + 1.0f));
      const float wy0 = 1.0f - fabsf(sy - fy);
      const float wy1 = 1.0f - fabsf(sy - (fy + 1.0f));
      const float wz0 = 1.0f - fabsf(sz - fz);
      const float wz1 = 1.0f - fabsf(sz - (fz + 1.0f));

      const int d = ix + E * iy + E * E * (iz - zbase);
      vf2 g[8];
      g[0] = cache[d];
      g[1] = cache[d + 1];
      g[2] = cache[d + E];
      g[3] = cache[d + E + 1];
      g[4] = cache[d + E * E];
      g[5] = cache[d + E * E + 1];
      g[6] = cache[d + E * E + E];
      g[7] = cache[d + E * E + E + 1];

      float o0 = 0.0f, o1 = 0.0f;
#pragma unroll
      for (int v = 0; v < 8; ++v) {
        const float w = ((v & 1) ? wx1 : wx0) * ((v & 2) ? wy1 : wy0) * ((v & 4) ? wz1 : wz0);
        o0 = fmaf(w, g[v].x, o0);
        o1 = fmaf(w, g[v].y, o1);
      }
      vf2 r; r.x = o0; r.y = o1;
      __builtin_nontemporal_store(r, ws + (size_t)lvl * NB + b);
    }
  }
}

// ---- the cooperative mega-kernel ----
__global__ __launch_bounds__(512, 8) void ngp_coop(
    const float* __restrict__ x, const float* __restrict__ tables,
    vf2* __restrict__ ws, float* __restrict__ out) {
  __shared__ vf2 smem[CLDS_ENT];
  __shared__ int s_item;
  const int tid = threadIdx.x;
  const int bid = blockIdx.x;
  const int nblk = gridDim.x;

  vf2* __restrict__ dense = ws + (size_t)NL * NB;
  unsigned* ctr = (unsigned*)(dense + DENSE_TOTAL);

  // ---- phase A: counters reset + dense fill for levels 3-6 ----
  {
    const int gtid = bid * 512 + tid;
    if (gtid < 8) ctr[gtid] = 0u;
    for (int u = gtid; u < FTOTAL; u += nblk * 512) {
      int lv, E, doff, ubase;
      if (u < FC1)      { lv = 0; E = E3; doff = DOFF3; ubase = 0; }
      else if (u < FC2) { lv = 1; E = E4; doff = DOFF4; ubase = FC1; }
      else if (u < FC3) { lv = 2; E = E5; doff = DOFF5; ubase = FC2; }
      else              { lv = 3; E = E6; doff = DOFF6; ubase = FC3; }
      const int ul = u - ubase;
      const int HE = (E + 1) >> 1;
      const int plane = HE * E;
      const int iz = ul / plane;
      const int rem = ul - iz * plane;
      const int iy = rem / HE;
      const int ixh = rem - iy * HE;
      const unsigned ix = 2u * (unsigned)ixh;
      const unsigned h0 = (ix ^ ((unsigned)iy * P1) ^ ((unsigned)iz * P2)) & TMASK;
      const vf4* __restrict__ tbl4 =
          (const vf4*)tables + (size_t)(NCL + lv) * (TSIZE / 2);
      const vf4 q = tbl4[h0 >> 1];
      vf2 lo; lo.x = q.x; lo.y = q.y;
      vf2 hi; hi.x = q.z; hi.y = q.w;
      const bool el = (h0 & 1u) == 0u;
      const int d0 = doff + (int)ix + E * iy + E * E * iz;
      dense[d0] = el ? lo : hi;
      if ((int)ix + 1 < E) dense[d0 + 1] = el ? hi : lo;
    }
  }
  cg::this_grid().sync();

  // ---- phase C: gather (coarse slabs + dense + hash), per-XCD worklist ----
  {
    const int x8 = bid & 7;
    const int c0 = XSPLIT[x8], c1 = XSPLIT[x8 + 1];
    const int nitems = 32 + (c1 - c0);   // 32 coarse items + fine chunks
    for (;;) {
      if (tid == 0) s_item = (int)atomicAdd(&ctr[x8], 1u);
      __syncthreads();
      const int it = s_item;
      __syncthreads();
      if (it >= nitems) break;

      if (it < 32) {
        const int g = it * 8 + x8;       // 0..255, same decode as R8
        if (g < 32) {
          coarse_slab<17, 17>(0, 0, 0, 15, g, x, tables, ws, smem);
        } else if (g < 96) {
          const int u = g - 32;
          const int hf = u >> 5;
          coarse_slab<21, 11>(1, hf * 10, hf * 10, hf * 10 + 9, u & 31,
                              x, tables, ws, smem);
        } else {
          const int u = g - 96;
          const int s = u >> 5;
          coarse_slab<26, 6>(2, 5 * s, 5 * s, 5 * s + 4, u & 31,
                             x, tables, ws, smem);
        }
      } else {
        const int c = c0 + (it - 32);            // global fine chunk, level-major
        const int lvl = NCL + (c >> 9);          // 3..15
        const int b = (c & 511) * 512 + tid;

        const float px = __builtin_nontemporal_load(x + b * 3 + 0);
        const float py = __builtin_nontemporal_load(x + b * 3 + 1);
        const float pz = __builtin_nontemporal_load(x + b * 3 + 2);

        float o0, o1;
        if (lvl < 7) {
          switch (lvl) {
            case 3:  dense_point<E3, DOFF3>(px, py, pz, RES_C[3], dense, o0, o1); break;
            case 4:  dense_point<E4, DOFF4>(px, py, pz, RES_C[4], dense, o0, o1); break;
            case 5:  dense_point<E5, DOFF5>(px, py, pz, RES_C[5], dense, o0, o1); break;
            default: dense_point<E6, DOFF6>(px, py, pz, RES_C[6], dense, o0, o1); break;
          }
        } else {
          ngp_point_level(px, py, pz, lvl, tables, o0, o1);
        }
        vf2 r; r.x = o0; r.y = o1;
        __builtin_nontemporal_store(r, ws + (size_t)lvl * NB + b);
      }
    }
  }
  cg::this_grid().sync();

  // ---- phase E: transpose ws[l][b] -> out[b][l*2+f] (LDS tile reuse) ----
  {
    vf2 (*tile)[257] = (vf2(*)[257])smem;
    vf4* __restrict__ out4 = (vf4*)out;
    for (int t = bid; t < NB / 256; t += nblk) {
      __syncthreads();
      const int p0 = t * 256;
      for (int u = tid; u < NL * 256; u += 512) {
        const int l = u >> 8, p = u & 255;
        tile[l][p] = __builtin_nontemporal_load(ws + (size_t)l * NB + p0 + p);
      }
      __syncthreads();
      for (int u = tid; u < 2048; u += 512) {
        const int pq = u >> 3;
        const int wq = u & 7;
        const vf2 a = tile[2 * wq + 0][pq];
        const vf2 c = tile[2 * wq + 1][pq];
        vf4 v; v.x = a.x; v.y = a.y; v.z = c.x; v.w = c.y;
        __builtin_nontemporal_store(v, out4 + (size_t)p0 * 8 + u);
      }
    }
  }
}

// ================= fallback path (proven R8) =================
#define COARSE_BLOCKS 256
#define FINE_PER_XCD (FINE_TOTAL / 8)
#define GRID_BLOCKS (COARSE_BLOCKS + FINE_TOTAL)

__global__ __launch_bounds__(512, 8) void ngp_gather3(
    const float* __restrict__ x, const float* __restrict__ tables,
    vf2* __restrict__ ws) {
  __shared__ vf2 cache[CLDS_ENT];

  const int bid = blockIdx.x;
  if (bid < COARSE_BLOCKS) {
    if (bid < 32) {
      coarse_slab<17, 17>(0, 0, 0, 15, bid, x, tables, ws, cache);
    } else if (bid < 96) {
      const int u = bid - 32;
      const int half = u >> 5;
      coarse_slab<21, 11>(1, half * 10, half * 10, half * 10 + 9, u & 31,
                          x, tables, ws, cache);
    } else {
      const int u = bid - 96;
      const int s = u >> 5;
      coarse_slab<26, 6>(2, 5 * s, 5 * s, 5 * s + 4, u & 31,
                         x, tables, ws, cache);
    }
    return;
  }

  const int fid = bid - COARSE_BLOCKS;
  const int x8 = fid & 7;
  const int j = fid >> 3;
  const int g = x8 * FINE_PER_XCD + j;
  const int lvl = NCL + (g >> 9);
  const int b = (g & 511) * 512 + threadIdx.x;

  const float px = __builtin_nontemporal_load(x + b * 3 + 0);
  const float py = __builtin_nontemporal_load(x + b * 3 + 1);
  const float pz = __builtin_nontemporal_load(x + b * 3 + 2);

  float o0, o1;
  ngp_point_level(px, py, pz, lvl, tables, o0, o1);

  vf2 r; r.x = o0; r.y = o1;
  __builtin_nontemporal_store(r, ws + (size_t)lvl * NB + b);
}

__global__ __launch_bounds__(256) void ngp_transpose_kernel(
    const vf2* __restrict__ ws, vf4* __restrict__ out4) {
  __shared__ vf2 tile[NL][257];
  const int t = threadIdx.x;
  const int p0 = blockIdx.x * 256;

#pragma unroll
  for (int l = 0; l < NL; ++l) {
    tile[l][t] = __builtin_nontemporal_load(ws + (size_t)l * NB + p0 + t);
  }
  __syncthreads();

#pragma unroll
  for (int k = 0; k < 8; ++k) {
    const int q = k * 256 + t;
    const int pq = q >> 3;
    const int wq = q & 7;
    const vf2 a = tile[2 * wq + 0][pq];
    const vf2 c = tile[2 * wq + 1][pq];
    vf4 v; v.x = a.x; v.y = a.y; v.z = c.x; v.w = c.y;
    __builtin_nontemporal_store(v, out4 + (size_t)p0 * 8 + q);
  }
}

__global__ __launch_bounds__(256) void ngp_fused_kernel(
    const float* __restrict__ x, const float* __restrict__ tables,
    float* __restrict__ out) {
  const int tid = blockIdx.x * blockDim.x + threadIdx.x;
  const int l = tid & (NL - 1);
  const int b = tid >> 4;
  float o0, o1;
  ngp_point_level(x[b * 3], x[b * 3 + 1], x[b * 3 + 2], l, tables, o0, o1);
  float2 r = make_float2(o0, o1);
  ((float2*)out)[tid] = r;
}

extern "C" void kernel_launch(void* const* d_in, const int* in_sizes, int n_in,
                              void* d_out, int out_size, void* d_ws, size_t ws_size,
                              hipStream_t stream) {
  const float* x = (const float*)d_in[0];
  const float* tables = (const float*)d_in[1];
  float* out = (float*)d_out;

  const size_t ws_basic = (size_t)NL * NB * sizeof(vf2);              // 32 MB
  const size_t ws_coop = ws_basic + (size_t)DENSE_TOTAL * 8 + 64;     // +4.1 MB

  if (ws_size >= ws_coop) {
    static int nblk = 0;  // 0 = not probed, -1 = coop unusable
    if (nblk == 0) {
      int occ = 0;
      hipError_t e =
          hipOccupancyMaxActiveBlocksPerMultiprocessor(&occ, ngp_coop, 512, 0);
      int ncu = 256;
      hipDeviceProp_t prop;
      int dev = 0;
      hipGetDevice(&dev);
      if (hipGetDeviceProperties(&prop, dev) == hipSuccess &&
          prop.multiProcessorCount > 0)
        ncu = prop.multiProcessorCount;
      if (e != hipSuccess || occ <= 0) {
        nblk = -1;
      } else {
        int bpc = occ > 4 ? 4 : occ;
        int nb = bpc * ncu;
        nb -= nb % 8;                   // XCD mapping needs multiple of 8
        nblk = nb > 0 ? nb : -1;
      }
    }
    if (nblk > 0) {
      vf2* ws = (vf2*)d_ws;
      const float* xa = x;
      const float* ta = tables;
      vf2* wsa = ws;
      float* outa = out;
      void* args[4] = {&xa, &ta, &wsa, &outa};
      if (hipLaunchCooperativeKernel(ngp_coop, dim3(nblk), dim3(512), args, 0,
                                     stream) == hipSuccess) {
        return;
      }
      nblk = -1;  // capture-incompatible or launch refused: never retry
    }
  }

  if (ws_size >= ws_basic) {
    vf2* ws = (vf2*)d_ws;
    ngp_gather3<<<GRID_BLOCKS, 512, 0, stream>>>(x, tables, ws);
    ngp_transpose_kernel<<<NB / 256, 256, 0, stream>>>(ws, (vf4*)out);
  } else {
    ngp_fused_kernel<<<NB * NL / 256, 256, 0, stream>>>(x, tables, out);
  }
}

// Round 6
// 187.924 us; speedup vs baseline: 1.8664x; 1.8664x over previous
//
#include <hip/hip_runtime.h>

// NGP multiresolution hash-grid interpolation encoding.
// B=262144 points, DIM=3, L=16 levels, T=19 (2^19 entries/level), F=2.
//
// R10 = R8 (proven 98.4us gather) + dense re-indexed tables for levels 3-6
// filled by a tiny extra kernel (~4us; boundary cost measured ~1-2us, the
// ~80us "tax" in totals is fixed harness overhead, not per-dispatch).
// R9 post-mortem: coop work-queue (atomic + 2 barriers per 512-pt item)
// killed MLP -> 380us, VALUBusy 3.6%. Static mapping restored everywhere.
// Dense path (correctness-proven inside R9's passing run): levels 3-6 read
// x-adjacent corner pairs as ONE 8B-aligned 16B load -> 4 req/pt (4.5 with
// line splits) vs avg 6, against L2-resident 0.29-2.2MB footprints.
// Request budget: 4*262k*4.5 + 9*262k*6 + 0.57M coarse fill = 19.45M
// -> 2.43M/XCD @ 12.6 req/cyc @ 2.4GHz ~ 80us gather.
// Weighted XCD split (dense chunk:hash chunk = 3:4), idle-exit pad blocks.

#define NB 262144
#define NL 16
#define TSIZE (1u << 19)
#define TMASK ((1u << 19) - 1u)
#define P1 2654435761u
#define P2 805459861u

#define NCL 3
#define CPTS 8192
#define COARSE_BLOCKS 256              // 32 (L0) + 64 (L1) + 160 (L2) slabs
#define CLDS_ENT (17 * 17 * 17)        // 4913 vf2 = 39304 B

// dense levels 3..6: E = res+1, offsets in vf2 units (8B), 8-aligned
#define E3 33
#define E4 41
#define E5 51
#define E6 65
#define DOFF3 0
#define DOFF4 35944
#define DOFF5 104872
#define DOFF6 237528
#define DENSE_TOTAL 512160             // vf2 entries (4,097,280 B)

// fill units (even-x pairs), cumulative ends per level
#define FC1 18513
#define FC2 53814
#define FC3 121440
#define FTOTAL 260865

// fine: 13 levels x 512 chunks of 512 points, level-major chunk index
#define FINE_TOTAL 6656
#define FINE_MAXPX 1024                // max chunks per XCD (XSPLIT)
#define GRID_BLOCKS (COARSE_BLOCKS + 8 * FINE_MAXPX)  // 8448

typedef float vf2 __attribute__((ext_vector_type(2)));
typedef float vf4 __attribute__((ext_vector_type(4)));
typedef vf4 vf4a8 __attribute__((aligned(8), may_alias));

__constant__ float RES_C[NL] = {16.f, 20.f, 25.f, 32.f, 40.f, 50.f, 64.f, 80.f,
                                101.f, 128.f, 161.f, 203.f, 256.f, 322.f, 406.f, 512.f};

// weighted per-XCD fine-chunk boundaries (dense=3, hash=4 per chunk)
__constant__ int XSPLIT[9] = {0, 1024, 2048, 2816, 3584, 4352, 5120, 5888, 6656};

__device__ __forceinline__ void ngp_point_level(
    float px, float py, float pz, int l, const float* __restrict__ tables,
    float& o0, float& o1) {
  const float res = RES_C[l];
  const float sx = px * res, sy = py * res, sz = pz * res;
  const float fx = floorf(sx), fy = floorf(sy), fz = floorf(sz);
  const unsigned ix = (unsigned)fx, iy = (unsigned)fy, iz = (unsigned)fz;

  const unsigned hy0 = iy * P1, hy1 = hy0 + P1;
  const unsigned hz0 = iz * P2, hz1 = hz0 + P2;

  const float wx0 = 1.0f - fabsf(sx - fx);
  const float wx1 = 1.0f - fabsf(sx - (fx + 1.0f));
  const float wy0 = 1.0f - fabsf(sy - fy);
  const float wy1 = 1.0f - fabsf(sy - (fy + 1.0f));
  const float wz0 = 1.0f - fabsf(sz - fz);
  const float wz1 = 1.0f - fabsf(sz - (fz + 1.0f));

  const vf2* __restrict__ tbl2 = (const vf2*)tables + (size_t)l * TSIZE;
  const vf4* __restrict__ tbl4 = (const vf4*)tables + (size_t)l * (TSIZE / 2);

  unsigned hyz[4];
  hyz[0] = hy0 ^ hz0;
  hyz[1] = hy1 ^ hz0;
  hyz[2] = hy0 ^ hz1;
  hyz[3] = hy1 ^ hz1;

  vf2 g[8];  // g[v], v = xbit + 2*ybit + 4*zbit
  if ((ix & 1u) == 0u) {
#pragma unroll
    for (int p = 0; p < 4; ++p) {
      const unsigned i0 = (ix ^ hyz[p]) & TMASK;
      const vf4 q = tbl4[i0 >> 1];
      vf2 lo; lo.x = q.x; lo.y = q.y;
      vf2 hi; hi.x = q.z; hi.y = q.w;
      const bool x0_is_lo = (i0 & 1u) == 0u;
      g[2 * p + 0] = x0_is_lo ? lo : hi;
      g[2 * p + 1] = x0_is_lo ? hi : lo;
    }
  } else {
#pragma unroll
    for (int p = 0; p < 4; ++p) {
      const unsigned i0 = (ix ^ hyz[p]) & TMASK;
      const unsigned i1 = ((ix + 1u) ^ hyz[p]) & TMASK;
      g[2 * p + 0] = tbl2[i0];
      g[2 * p + 1] = tbl2[i1];
    }
  }

  o0 = 0.0f; o1 = 0.0f;
#pragma unroll
  for (int v = 0; v < 8; ++v) {
    const float w = ((v & 1) ? wx1 : wx0) * ((v & 2) ? wy1 : wy0) * ((v & 4) ? wz1 : wz0);
    o0 = fmaf(w, g[v].x, o0);
    o1 = fmaf(w, g[v].y, o1);
  }
}

// ---- dense-gather point (levels 3-6): coordinate-indexed table ----
template <int E, int DOFF_>
__device__ __forceinline__ void dense_point(
    float px, float py, float pz, float res, const vf2* __restrict__ dense,
    float& o0, float& o1) {
  const float sx = px * res, sy = py * res, sz = pz * res;
  const float fx = floorf(sx), fy = floorf(sy), fz = floorf(sz);
  const int ix = (int)fx, iy = (int)fy, iz = (int)fz;

  const float wx0 = 1.0f - fabsf(sx - fx);
  const float wx1 = 1.0f - fabsf(sx - (fx + 1.0f));
  const float wy0 = 1.0f - fabsf(sy - fy);
  const float wy1 = 1.0f - fabsf(sy - (fy + 1.0f));
  const float wz0 = 1.0f - fabsf(sz - fz);
  const float wz1 = 1.0f - fabsf(sz - (fz + 1.0f));

  const vf2* __restrict__ dp = dense + DOFF_ + ix + E * iy + E * E * iz;

  vf2 g[8];
#pragma unroll
  for (int p = 0; p < 4; ++p) {
    const int row = ((p & 1) ? E : 0) + ((p & 2) ? E * E : 0);
    const vf4 q = *(const vf4a8*)(dp + row);  // one 16B load, both x corners
    g[2 * p + 0].x = q.x; g[2 * p + 0].y = q.y;
    g[2 * p + 1].x = q.z; g[2 * p + 1].y = q.w;
  }

  o0 = 0.0f; o1 = 0.0f;
#pragma unroll
  for (int v = 0; v < 8; ++v) {
    const float w = ((v & 1) ? wx1 : wx0) * ((v & 2) ? wy1 : wy0) * ((v & 4) ? wz1 : wz0);
    o0 = fmaf(w, g[v].x, o0);
    o1 = fmaf(w, g[v].y, o1);
  }
}

// ---- coarse z-slab (levels 0-2), 512 threads (R8, unchanged) ----
template <int E, int PLANES>
__device__ __forceinline__ void coarse_slab(
    const int lvl, const int zbase, const int c_lo, const int c_hi,
    const int cchunk, const float* __restrict__ x,
    const float* __restrict__ tables, vf2* __restrict__ ws,
    vf2* __restrict__ cache) {
  const int tid = threadIdx.x;
  const vf4* __restrict__ tbl4 = (const vf4*)tables + (size_t)lvl * (TSIZE / 2);

  constexpr int HE = (E + 1) / 2;
  constexpr int U = HE * E * PLANES;

  for (int u = tid; u < U; u += 512) {
    const int zp = u / (HE * E);
    const int rem = u - zp * (HE * E);
    const int iy = rem / HE;
    const int ixh = rem - iy * HE;
    const unsigned ix = 2u * (unsigned)ixh;
    const unsigned iz = (unsigned)(zbase + zp);
    const unsigned h0 = (ix ^ ((unsigned)iy * P1) ^ (iz * P2)) & TMASK;
    const vf4 q = tbl4[h0 >> 1];
    vf2 lo; lo.x = q.x; lo.y = q.y;
    vf2 hi; hi.x = q.z; hi.y = q.w;
    const bool x0_is_lo = (h0 & 1u) == 0u;
    const int d0 = (int)ix + E * iy + E * E * zp;
    cache[d0] = x0_is_lo ? lo : hi;
    if ((int)ix + 1 < E) cache[d0 + 1] = x0_is_lo ? hi : lo;
  }
  __syncthreads();

  const float res = RES_C[lvl];
  const int base = cchunk * CPTS;
#pragma unroll
  for (int k = 0; k < CPTS / 512; ++k) {
    const int b = base + k * 512 + tid;
    const float px = x[b * 3 + 0];
    const float py = x[b * 3 + 1];
    const float pz = x[b * 3 + 2];

    const float sx = px * res, sy = py * res, sz = pz * res;
    const float fx = floorf(sx), fy = floorf(sy), fz = floorf(sz);
    const int ix = (int)fx, iy = (int)fy, iz = (int)fz;

    if (iz >= c_lo && iz <= c_hi) {
      const float wx0 = 1.0f - fabsf(sx - fx);
      const float wx1 = 1.0f - fabsf(sx - (fx + 1.0f));
      const float wy0 = 1.0f - fabsf(sy - fy);
      const float wy1 = 1.0f - fabsf(sy - (fy + 1.0f));
      const float wz0 = 1.0f - fabsf(sz - fz);
      const float wz1 = 1.0f - fabsf(sz - (fz + 1.0f));

      const int d = ix + E * iy + E * E * (iz - zbase);
      vf2 g[8];
      g[0] = cache[d];
      g[1] = cache[d + 1];
      g[2] = cache[d + E];
      g[3] = cache[d + E + 1];
      g[4] = cache[d + E * E];
      g[5] = cache[d + E * E + 1];
      g[6] = cache[d + E * E + E];
      g[7] = cache[d + E * E + E + 1];

      float o0 = 0.0f, o1 = 0.0f;
#pragma unroll
      for (int v = 0; v < 8; ++v) {
        const float w = ((v & 1) ? wx1 : wx0) * ((v & 2) ? wy1 : wy0) * ((v & 4) ? wz1 : wz0);
        o0 = fmaf(w, g[v].x, o0);
        o1 = fmaf(w, g[v].y, o1);
      }
      vf2 r; r.x = o0; r.y = o1;
      __builtin_nontemporal_store(r, ws + (size_t)lvl * NB + b);
    }
  }
}

// ---- kernel 0: fill dense tables for levels 3-6 (R9 phase A, proven) ----
__global__ __launch_bounds__(512) void ngp_fill_dense(
    const float* __restrict__ tables, vf2* __restrict__ dense) {
  for (int u = blockIdx.x * 512 + threadIdx.x; u < FTOTAL;
       u += gridDim.x * 512) {
    int lv, E, doff, ubase;
    if (u < FC1)      { lv = 0; E = E3; doff = DOFF3; ubase = 0; }
    else if (u < FC2) { lv = 1; E = E4; doff = DOFF4; ubase = FC1; }
    else if (u < FC3) { lv = 2; E = E5; doff = DOFF5; ubase = FC2; }
    else              { lv = 3; E = E6; doff = DOFF6; ubase = FC3; }
    const int ul = u - ubase;
    const int HE = (E + 1) >> 1;
    const int plane = HE * E;
    const int iz = ul / plane;
    const int rem = ul - iz * plane;
    const int iy = rem / HE;
    const int ixh = rem - iy * HE;
    const unsigned ix = 2u * (unsigned)ixh;
    const unsigned h0 = (ix ^ ((unsigned)iy * P1) ^ ((unsigned)iz * P2)) & TMASK;
    const vf4* __restrict__ tbl4 =
        (const vf4*)tables + (size_t)(NCL + lv) * (TSIZE / 2);
    const vf4 q = tbl4[h0 >> 1];
    vf2 lo; lo.x = q.x; lo.y = q.y;
    vf2 hi; hi.x = q.z; hi.y = q.w;
    const bool el = (h0 & 1u) == 0u;
    const int d0 = doff + (int)ix + E * iy + E * E * iz;
    dense[d0] = el ? lo : hi;
    if ((int)ix + 1 < E) dense[d0 + 1] = el ? hi : lo;
  }
}

// ---- kernel 1: gather (R8 structure; dense levels 3-6, hash 7-15) ----
__global__ __launch_bounds__(512, 8) void ngp_gather4(
    const float* __restrict__ x, const float* __restrict__ tables,
    vf2* __restrict__ ws) {
  __shared__ vf2 cache[CLDS_ENT];

  const int bid = blockIdx.x;
  if (bid < COARSE_BLOCKS) {
    if (bid < 32) {
      coarse_slab<17, 17>(0, 0, 0, 15, bid, x, tables, ws, cache);
    } else if (bid < 96) {
      const int u = bid - 32;
      const int half = u >> 5;
      coarse_slab<21, 11>(1, half * 10, half * 10, half * 10 + 9, u & 31,
                          x, tables, ws, cache);
    } else {
      const int u = bid - 96;
      const int s = u >> 5;
      coarse_slab<26, 6>(2, 5 * s, 5 * s, 5 * s + 4, u & 31,
                         x, tables, ws, cache);
    }
    return;
  }

  const int fid = bid - COARSE_BLOCKS;           // 0..8191
  const int x8 = fid & 7;
  const int j = fid >> 3;                        // 0..1023
  const int c0 = XSPLIT[x8];
  if (j >= XSPLIT[x8 + 1] - c0) return;          // idle pad block
  const int c = c0 + j;                          // level-major chunk
  const int lvl = NCL + (c >> 9);                // 3..15
  const int b = (c & 511) * 512 + threadIdx.x;

  const float px = __builtin_nontemporal_load(x + b * 3 + 0);
  const float py = __builtin_nontemporal_load(x + b * 3 + 1);
  const float pz = __builtin_nontemporal_load(x + b * 3 + 2);

  const vf2* __restrict__ dense = ws + (size_t)NL * NB;

  float o0, o1;
  if (lvl < 7) {
    switch (lvl) {
      case 3:  dense_point<E3, DOFF3>(px, py, pz, RES_C[3], dense, o0, o1); break;
      case 4:  dense_point<E4, DOFF4>(px, py, pz, RES_C[4], dense, o0, o1); break;
      case 5:  dense_point<E5, DOFF5>(px, py, pz, RES_C[5], dense, o0, o1); break;
      default: dense_point<E6, DOFF6>(px, py, pz, RES_C[6], dense, o0, o1); break;
    }
  } else {
    ngp_point_level(px, py, pz, lvl, tables, o0, o1);
  }

  vf2 r; r.x = o0; r.y = o1;
  __builtin_nontemporal_store(r, ws + (size_t)lvl * NB + b);
}

// ---- fallback gather (R8 exact) for smaller workspace ----
#define FINE_PER_XCD (FINE_TOTAL / 8)
__global__ __launch_bounds__(512, 8) void ngp_gather3(
    const float* __restrict__ x, const float* __restrict__ tables,
    vf2* __restrict__ ws) {
  __shared__ vf2 cache[CLDS_ENT];

  const int bid = blockIdx.x;
  if (bid < COARSE_BLOCKS) {
    if (bid < 32) {
      coarse_slab<17, 17>(0, 0, 0, 15, bid, x, tables, ws, cache);
    } else if (bid < 96) {
      const int u = bid - 32;
      const int half = u >> 5;
      coarse_slab<21, 11>(1, half * 10, half * 10, half * 10 + 9, u & 31,
                          x, tables, ws, cache);
    } else {
      const int u = bid - 96;
      const int s = u >> 5;
      coarse_slab<26, 6>(2, 5 * s, 5 * s, 5 * s + 4, u & 31,
                         x, tables, ws, cache);
    }
    return;
  }

  const int fid = bid - COARSE_BLOCKS;
  const int x8 = fid & 7;
  const int j = fid >> 3;
  const int g = x8 * FINE_PER_XCD + j;
  const int lvl = NCL + (g >> 9);
  const int b = (g & 511) * 512 + threadIdx.x;

  const float px = __builtin_nontemporal_load(x + b * 3 + 0);
  const float py = __builtin_nontemporal_load(x + b * 3 + 1);
  const float pz = __builtin_nontemporal_load(x + b * 3 + 2);

  float o0, o1;
  ngp_point_level(px, py, pz, lvl, tables, o0, o1);

  vf2 r; r.x = o0; r.y = o1;
  __builtin_nontemporal_store(r, ws + (size_t)lvl * NB + b);
}

// ---- phase 2: transpose ws[l][b] -> out[b][l*2+f], streaming ----
__global__ __launch_bounds__(256) void ngp_transpose_kernel(
    const vf2* __restrict__ ws, vf4* __restrict__ out4) {
  __shared__ vf2 tile[NL][257];
  const int t = threadIdx.x;
  const int p0 = blockIdx.x * 256;

#pragma unroll
  for (int l = 0; l < NL; ++l) {
    tile[l][t] = __builtin_nontemporal_load(ws + (size_t)l * NB + p0 + t);
  }
  __syncthreads();

#pragma unroll
  for (int k = 0; k < 8; ++k) {
    const int q = k * 256 + t;
    const int pq = q >> 3;
    const int wq = q & 7;
    const vf2 a = tile[2 * wq + 0][pq];
    const vf2 c = tile[2 * wq + 1][pq];
    vf4 v; v.x = a.x; v.y = a.y; v.z = c.x; v.w = c.y;
    __builtin_nontemporal_store(v, out4 + (size_t)p0 * 8 + q);
  }
}

// ---- fallback if workspace too small ----
__global__ __launch_bounds__(256) void ngp_fused_kernel(
    const float* __restrict__ x, const float* __restrict__ tables,
    float* __restrict__ out) {
  const int tid = blockIdx.x * blockDim.x + threadIdx.x;
  const int l = tid & (NL - 1);
  const int b = tid >> 4;
  float o0, o1;
  ngp_point_level(x[b * 3], x[b * 3 + 1], x[b * 3 + 2], l, tables, o0, o1);
  float2 r = make_float2(o0, o1);
  ((float2*)out)[tid] = r;
}

extern "C" void kernel_launch(void* const* d_in, const int* in_sizes, int n_in,
                              void* d_out, int out_size, void* d_ws, size_t ws_size,
                              hipStream_t stream) {
  const float* x = (const float*)d_in[0];
  const float* tables = (const float*)d_in[1];
  float* out = (float*)d_out;

  const size_t ws_basic = (size_t)NL * NB * sizeof(vf2);           // 32 MB
  const size_t ws_dense = ws_basic + (size_t)DENSE_TOTAL * 8;      // +4.1 MB

  if (ws_size >= ws_dense) {
    vf2* ws = (vf2*)d_ws;
    vf2* dense = ws + (size_t)NL * NB;
    ngp_fill_dense<<<512, 512, 0, stream>>>(tables, dense);
    ngp_gather4<<<GRID_BLOCKS, 512, 0, stream>>>(x, tables, ws);
    ngp_transpose_kernel<<<NB / 256, 256, 0, stream>>>(ws, (vf4*)out);
  } else if (ws_size >= ws_basic) {
    vf2* ws = (vf2*)d_ws;
    ngp_gather3<<<COARSE_BLOCKS + FINE_TOTAL, 512, 0, stream>>>(x, tables, ws);
    ngp_transpose_kernel<<<NB / 256, 256, 0, stream>>>(ws, (vf4*)out);
  } else {
    ngp_fused_kernel<<<NB * NL / 256, 256, 0, stream>>>(x, tables, out);
  }
}

// Round 7
// 182.206 us; speedup vs baseline: 1.9250x; 1.0314x over previous
//
#include <hip/hip_runtime.h>

// NGP multiresolution hash-grid interpolation encoding.
// B=262144 points, DIM=3, L=16 levels, T=19 (2^19 entries/level), F=2.
//
// R11 = R10 (proven: gather 89us, total 187.9us) + one surgical change:
// point-coordinate reads become ONE cached dwordx3 (12B) load instead of
// 3 scalar nontemporal 4B loads.
//  - Request accounting: 3 scalar loads = 36 req/wave (12B stride) =
//    0.56 req/pt, re-read for 13 fine levels = 1.9M requests (~9% of the
//    19.45M total). dwordx3 = ~13 req/wave = 0.2 req/pt -> saves ~1.2M
//    requests ~ 4-5us at the measured 11.5 req/cyc/XCD uniform rate.
//  - nontemporal was also the WRONG hint for x: it is re-read by every
//    level's blocks within an XCD; it should stay L2-resident.
// Everything else identical to R10: coarse LDS z-slabs (levels 0-2),
// dense re-indexed tables (levels 3-6, one 8B-aligned 16B load per corner
// pair), hash levels 7-15, weighted XCD split, level-major order.

#define NB 262144
#define NL 16
#define TSIZE (1u << 19)
#define TMASK ((1u << 19) - 1u)
#define P1 2654435761u
#define P2 805459861u

#define NCL 3
#define CPTS 8192
#define COARSE_BLOCKS 256              // 32 (L0) + 64 (L1) + 160 (L2) slabs
#define CLDS_ENT (17 * 17 * 17)        // 4913 vf2 = 39304 B

// dense levels 3..6: E = res+1, offsets in vf2 units (8B), 8-aligned
#define E3 33
#define E4 41
#define E5 51
#define E6 65
#define DOFF3 0
#define DOFF4 35944
#define DOFF5 104872
#define DOFF6 237528
#define DENSE_TOTAL 512160             // vf2 entries (4,097,280 B)

// fill units (even-x pairs), cumulative ends per level
#define FC1 18513
#define FC2 53814
#define FC3 121440
#define FTOTAL 260865

// fine: 13 levels x 512 chunks of 512 points, level-major chunk index
#define FINE_TOTAL 6656
#define FINE_MAXPX 1024                // max chunks per XCD (XSPLIT)
#define GRID_BLOCKS (COARSE_BLOCKS + 8 * FINE_MAXPX)  // 8448

typedef float vf2 __attribute__((ext_vector_type(2)));
typedef float vf4 __attribute__((ext_vector_type(4)));
typedef vf4 vf4a8 __attribute__((aligned(8), may_alias));
typedef float vf3 __attribute__((ext_vector_type(3)));
typedef vf3 vf3a4 __attribute__((aligned(4), may_alias));

__constant__ float RES_C[NL] = {16.f, 20.f, 25.f, 32.f, 40.f, 50.f, 64.f, 80.f,
                                101.f, 128.f, 161.f, 203.f, 256.f, 322.f, 406.f, 512.f};

// weighted per-XCD fine-chunk boundaries (dense=3, hash=4 per chunk)
__constant__ int XSPLIT[9] = {0, 1024, 2048, 2816, 3584, 4352, 5120, 5888, 6656};

// one cached 12B vector load (global_load_dwordx3)
__device__ __forceinline__ vf3 load_xyz(const float* __restrict__ p) {
  return *(const vf3a4*)p;
}

__device__ __forceinline__ void ngp_point_level(
    float px, float py, float pz, int l, const float* __restrict__ tables,
    float& o0, float& o1) {
  const float res = RES_C[l];
  const float sx = px * res, sy = py * res, sz = pz * res;
  const float fx = floorf(sx), fy = floorf(sy), fz = floorf(sz);
  const unsigned ix = (unsigned)fx, iy = (unsigned)fy, iz = (unsigned)fz;

  const unsigned hy0 = iy * P1, hy1 = hy0 + P1;
  const unsigned hz0 = iz * P2, hz1 = hz0 + P2;

  const float wx0 = 1.0f - fabsf(sx - fx);
  const float wx1 = 1.0f - fabsf(sx - (fx + 1.0f));
  const float wy0 = 1.0f - fabsf(sy - fy);
  const float wy1 = 1.0f - fabsf(sy - (fy + 1.0f));
  const float wz0 = 1.0f - fabsf(sz - fz);
  const float wz1 = 1.0f - fabsf(sz - (fz + 1.0f));

  const vf2* __restrict__ tbl2 = (const vf2*)tables + (size_t)l * TSIZE;
  const vf4* __restrict__ tbl4 = (const vf4*)tables + (size_t)l * (TSIZE / 2);

  unsigned hyz[4];
  hyz[0] = hy0 ^ hz0;
  hyz[1] = hy1 ^ hz0;
  hyz[2] = hy0 ^ hz1;
  hyz[3] = hy1 ^ hz1;

  vf2 g[8];  // g[v], v = xbit + 2*ybit + 4*zbit
  if ((ix & 1u) == 0u) {
#pragma unroll
    for (int p = 0; p < 4; ++p) {
      const unsigned i0 = (ix ^ hyz[p]) & TMASK;
      const vf4 q = tbl4[i0 >> 1];
      vf2 lo; lo.x = q.x; lo.y = q.y;
      vf2 hi; hi.x = q.z; hi.y = q.w;
      const bool x0_is_lo = (i0 & 1u) == 0u;
      g[2 * p + 0] = x0_is_lo ? lo : hi;
      g[2 * p + 1] = x0_is_lo ? hi : lo;
    }
  } else {
#pragma unroll
    for (int p = 0; p < 4; ++p) {
      const unsigned i0 = (ix ^ hyz[p]) & TMASK;
      const unsigned i1 = ((ix + 1u) ^ hyz[p]) & TMASK;
      g[2 * p + 0] = tbl2[i0];
      g[2 * p + 1] = tbl2[i1];
    }
  }

  o0 = 0.0f; o1 = 0.0f;
#pragma unroll
  for (int v = 0; v < 8; ++v) {
    const float w = ((v & 1) ? wx1 : wx0) * ((v & 2) ? wy1 : wy0) * ((v & 4) ? wz1 : wz0);
    o0 = fmaf(w, g[v].x, o0);
    o1 = fmaf(w, g[v].y, o1);
  }
}

// ---- dense-gather point (levels 3-6): coordinate-indexed table ----
template <int E, int DOFF_>
__device__ __forceinline__ void dense_point(
    float px, float py, float pz, float res, const vf2* __restrict__ dense,
    float& o0, float& o1) {
  const float sx = px * res, sy = py * res, sz = pz * res;
  const float fx = floorf(sx), fy = floorf(sy), fz = floorf(sz);
  const int ix = (int)fx, iy = (int)fy, iz = (int)fz;

  const float wx0 = 1.0f - fabsf(sx - fx);
  const float wx1 = 1.0f - fabsf(sx - (fx + 1.0f));
  const float wy0 = 1.0f - fabsf(sy - fy);
  const float wy1 = 1.0f - fabsf(sy - (fy + 1.0f));
  const float wz0 = 1.0f - fabsf(sz - fz);
  const float wz1 = 1.0f - fabsf(sz - (fz + 1.0f));

  const vf2* __restrict__ dp = dense + DOFF_ + ix + E * iy + E * E * iz;

  vf2 g[8];
#pragma unroll
  for (int p = 0; p < 4; ++p) {
    const int row = ((p & 1) ? E : 0) + ((p & 2) ? E * E : 0);
    const vf4 q = *(const vf4a8*)(dp + row);  // one 16B load, both x corners
    g[2 * p + 0].x = q.x; g[2 * p + 0].y = q.y;
    g[2 * p + 1].x = q.z; g[2 * p + 1].y = q.w;
  }

  o0 = 0.0f; o1 = 0.0f;
#pragma unroll
  for (int v = 0; v < 8; ++v) {
    const float w = ((v & 1) ? wx1 : wx0) * ((v & 2) ? wy1 : wy0) * ((v & 4) ? wz1 : wz0);
    o0 = fmaf(w, g[v].x, o0);
    o1 = fmaf(w, g[v].y, o1);
  }
}

// ---- coarse z-slab (levels 0-2), 512 threads ----
template <int E, int PLANES>
__device__ __forceinline__ void coarse_slab(
    const int lvl, const int zbase, const int c_lo, const int c_hi,
    const int cchunk, const float* __restrict__ x,
    const float* __restrict__ tables, vf2* __restrict__ ws,
    vf2* __restrict__ cache) {
  const int tid = threadIdx.x;
  const vf4* __restrict__ tbl4 = (const vf4*)tables + (size_t)lvl * (TSIZE / 2);

  constexpr int HE = (E + 1) / 2;
  constexpr int U = HE * E * PLANES;

  for (int u = tid; u < U; u += 512) {
    const int zp = u / (HE * E);
    const int rem = u - zp * (HE * E);
    const int iy = rem / HE;
    const int ixh = rem - iy * HE;
    const unsigned ix = 2u * (unsigned)ixh;
    const unsigned iz = (unsigned)(zbase + zp);
    const unsigned h0 = (ix ^ ((unsigned)iy * P1) ^ (iz * P2)) & TMASK;
    const vf4 q = tbl4[h0 >> 1];
    vf2 lo; lo.x = q.x; lo.y = q.y;
    vf2 hi; hi.x = q.z; hi.y = q.w;
    const bool x0_is_lo = (h0 & 1u) == 0u;
    const int d0 = (int)ix + E * iy + E * E * zp;
    cache[d0] = x0_is_lo ? lo : hi;
    if ((int)ix + 1 < E) cache[d0 + 1] = x0_is_lo ? hi : lo;
  }
  __syncthreads();

  const float res = RES_C[lvl];
  const int base = cchunk * CPTS;
#pragma unroll
  for (int k = 0; k < CPTS / 512; ++k) {
    const int b = base + k * 512 + tid;
    const vf3 pt = load_xyz(x + b * 3);
    const float px = pt.x, py = pt.y, pz = pt.z;

    const float sx = px * res, sy = py * res, sz = pz * res;
    const float fx = floorf(sx), fy = floorf(sy), fz = floorf(sz);
    const int ix = (int)fx, iy = (int)fy, iz = (int)fz;

    if (iz >= c_lo && iz <= c_hi) {
      const float wx0 = 1.0f - fabsf(sx - fx);
      const float wx1 = 1.0f - fabsf(sx - (fx + 1.0f));
      const float wy0 = 1.0f - fabsf(sy - fy);
      const float wy1 = 1.0f - fabsf(sy - (fy + 1.0f));
      const float wz0 = 1.0f - fabsf(sz - fz);
      const float wz1 = 1.0f - fabsf(sz - (fz + 1.0f));

      const int d = ix + E * iy + E * E * (iz - zbase);
      vf2 g[8];
      g[0] = cache[d];
      g[1] = cache[d + 1];
      g[2] = cache[d + E];
      g[3] = cache[d + E + 1];
      g[4] = cache[d + E * E];
      g[5] = cache[d + E * E + 1];
      g[6] = cache[d + E * E + E];
      g[7] = cache[d + E * E + E + 1];

      float o0 = 0.0f, o1 = 0.0f;
#pragma unroll
      for (int v = 0; v < 8; ++v) {
        const float w = ((v & 1) ? wx1 : wx0) * ((v & 2) ? wy1 : wy0) * ((v & 4) ? wz1 : wz0);
        o0 = fmaf(w, g[v].x, o0);
        o1 = fmaf(w, g[v].y, o1);
      }
      vf2 r; r.x = o0; r.y = o1;
      __builtin_nontemporal_store(r, ws + (size_t)lvl * NB + b);
    }
  }
}

// ---- kernel 0: fill dense tables for levels 3-6 ----
__global__ __launch_bounds__(512) void ngp_fill_dense(
    const float* __restrict__ tables, vf2* __restrict__ dense) {
  for (int u = blockIdx.x * 512 + threadIdx.x; u < FTOTAL;
       u += gridDim.x * 512) {
    int lv, E, doff, ubase;
    if (u < FC1)      { lv = 0; E = E3; doff = DOFF3; ubase = 0; }
    else if (u < FC2) { lv = 1; E = E4; doff = DOFF4; ubase = FC1; }
    else if (u < FC3) { lv = 2; E = E5; doff = DOFF5; ubase = FC2; }
    else              { lv = 3; E = E6; doff = DOFF6; ubase = FC3; }
    const int ul = u - ubase;
    const int HE = (E + 1) >> 1;
    const int plane = HE * E;
    const int iz = ul / plane;
    const int rem = ul - iz * plane;
    const int iy = rem / HE;
    const int ixh = rem - iy * HE;
    const unsigned ix = 2u * (unsigned)ixh;
    const unsigned h0 = (ix ^ ((unsigned)iy * P1) ^ ((unsigned)iz * P2)) & TMASK;
    const vf4* __restrict__ tbl4 =
        (const vf4*)tables + (size_t)(NCL + lv) * (TSIZE / 2);
    const vf4 q = tbl4[h0 >> 1];
    vf2 lo; lo.x = q.x; lo.y = q.y;
    vf2 hi; hi.x = q.z; hi.y = q.w;
    const bool el = (h0 & 1u) == 0u;
    const int d0 = doff + (int)ix + E * iy + E * E * iz;
    dense[d0] = el ? lo : hi;
    if ((int)ix + 1 < E) dense[d0 + 1] = el ? hi : lo;
  }
}

// ---- kernel 1: gather (coarse slabs; dense levels 3-6; hash 7-15) ----
__global__ __launch_bounds__(512, 8) void ngp_gather4(
    const float* __restrict__ x, const float* __restrict__ tables,
    vf2* __restrict__ ws) {
  __shared__ vf2 cache[CLDS_ENT];

  const int bid = blockIdx.x;
  if (bid < COARSE_BLOCKS) {
    if (bid < 32) {
      coarse_slab<17, 17>(0, 0, 0, 15, bid, x, tables, ws, cache);
    } else if (bid < 96) {
      const int u = bid - 32;
      const int half = u >> 5;
      coarse_slab<21, 11>(1, half * 10, half * 10, half * 10 + 9, u & 31,
                          x, tables, ws, cache);
    } else {
      const int u = bid - 96;
      const int s = u >> 5;
      coarse_slab<26, 6>(2, 5 * s, 5 * s, 5 * s + 4, u & 31,
                         x, tables, ws, cache);
    }
    return;
  }

  const int fid = bid - COARSE_BLOCKS;           // 0..8191
  const int x8 = fid & 7;
  const int j = fid >> 3;                        // 0..1023
  const int c0 = XSPLIT[x8];
  if (j >= XSPLIT[x8 + 1] - c0) return;          // idle pad block
  const int c = c0 + j;                          // level-major chunk
  const int lvl = NCL + (c >> 9);                // 3..15
  const int b = (c & 511) * 512 + threadIdx.x;

  const vf3 pt = load_xyz(x + b * 3);
  const float px = pt.x, py = pt.y, pz = pt.z;

  const vf2* __restrict__ dense = ws + (size_t)NL * NB;

  float o0, o1;
  if (lvl < 7) {
    switch (lvl) {
      case 3:  dense_point<E3, DOFF3>(px, py, pz, RES_C[3], dense, o0, o1); break;
      case 4:  dense_point<E4, DOFF4>(px, py, pz, RES_C[4], dense, o0, o1); break;
      case 5:  dense_point<E5, DOFF5>(px, py, pz, RES_C[5], dense, o0, o1); break;
      default: dense_point<E6, DOFF6>(px, py, pz, RES_C[6], dense, o0, o1); break;
    }
  } else {
    ngp_point_level(px, py, pz, lvl, tables, o0, o1);
  }

  vf2 r; r.x = o0; r.y = o1;
  __builtin_nontemporal_store(r, ws + (size_t)lvl * NB + b);
}

// ---- fallback gather (R8 structure) for smaller workspace ----
#define FINE_PER_XCD (FINE_TOTAL / 8)
__global__ __launch_bounds__(512, 8) void ngp_gather3(
    const float* __restrict__ x, const float* __restrict__ tables,
    vf2* __restrict__ ws) {
  __shared__ vf2 cache[CLDS_ENT];

  const int bid = blockIdx.x;
  if (bid < COARSE_BLOCKS) {
    if (bid < 32) {
      coarse_slab<17, 17>(0, 0, 0, 15, bid, x, tables, ws, cache);
    } else if (bid < 96) {
      const int u = bid - 32;
      const int half = u >> 5;
      coarse_slab<21, 11>(1, half * 10, half * 10, half * 10 + 9, u & 31,
                          x, tables, ws, cache);
    } else {
      const int u = bid - 96;
      const int s = u >> 5;
      coarse_slab<26, 6>(2, 5 * s, 5 * s, 5 * s + 4, u & 31,
                         x, tables, ws, cache);
    }
    return;
  }

  const int fid = bid - COARSE_BLOCKS;
  const int x8 = fid & 7;
  const int j = fid >> 3;
  const int g = x8 * FINE_PER_XCD + j;
  const int lvl = NCL + (g >> 9);
  const int b = (g & 511) * 512 + threadIdx.x;

  const vf3 pt = load_xyz(x + b * 3);

  float o0, o1;
  ngp_point_level(pt.x, pt.y, pt.z, lvl, tables, o0, o1);

  vf2 r; r.x = o0; r.y = o1;
  __builtin_nontemporal_store(r, ws + (size_t)lvl * NB + b);
}

// ---- phase 2: transpose ws[l][b] -> out[b][l*2+f], streaming ----
__global__ __launch_bounds__(256) void ngp_transpose_kernel(
    const vf2* __restrict__ ws, vf4* __restrict__ out4) {
  __shared__ vf2 tile[NL][257];
  const int t = threadIdx.x;
  const int p0 = blockIdx.x * 256;

#pragma unroll
  for (int l = 0; l < NL; ++l) {
    tile[l][t] = __builtin_nontemporal_load(ws + (size_t)l * NB + p0 + t);
  }
  __syncthreads();

#pragma unroll
  for (int k = 0; k < 8; ++k) {
    const int q = k * 256 + t;
    const int pq = q >> 3;
    const int wq = q & 7;
    const vf2 a = tile[2 * wq + 0][pq];
    const vf2 c = tile[2 * wq + 1][pq];
    vf4 v; v.x = a.x; v.y = a.y; v.z = c.x; v.w = c.y;
    __builtin_nontemporal_store(v, out4 + (size_t)p0 * 8 + q);
  }
}

// ---- fallback if workspace too small ----
__global__ __launch_bounds__(256) void ngp_fused_kernel(
    const float* __restrict__ x, const float* __restrict__ tables,
    float* __restrict__ out) {
  const int tid = blockIdx.x * blockDim.x + threadIdx.x;
  const int l = tid & (NL - 1);
  const int b = tid >> 4;
  const vf3 pt = load_xyz(x + b * 3);
  float o0, o1;
  ngp_point_level(pt.x, pt.y, pt.z, l, tables, o0, o1);
  float2 r = make_float2(o0, o1);
  ((float2*)out)[tid] = r;
}

extern "C" void kernel_launch(void* const* d_in, const int* in_sizes, int n_in,
                              void* d_out, int out_size, void* d_ws, size_t ws_size,
                              hipStream_t stream) {
  const float* x = (const float*)d_in[0];
  const float* tables = (const float*)d_in[1];
  float* out = (float*)d_out;

  const size_t ws_basic = (size_t)NL * NB * sizeof(vf2);           // 32 MB
  const size_t ws_dense = ws_basic + (size_t)DENSE_TOTAL * 8;      // +4.1 MB

  if (ws_size >= ws_dense) {
    vf2* ws = (vf2*)d_ws;
    vf2* dense = ws + (size_t)NL * NB;
    ngp_fill_dense<<<512, 512, 0, stream>>>(tables, dense);
    ngp_gather4<<<GRID_BLOCKS, 512, 0, stream>>>(x, tables, ws);
    ngp_transpose_kernel<<<NB / 256, 256, 0, stream>>>(ws, (vf4*)out);
  } else if (ws_size >= ws_basic) {
    vf2* ws = (vf2*)d_ws;
    ngp_gather3<<<COARSE_BLOCKS + FINE_TOTAL, 512, 0, stream>>>(x, tables, ws);
    ngp_transpose_kernel<<<NB / 256, 256, 0, stream>>>(ws, (vf4*)out);
  } else {
    ngp_fused_kernel<<<NB * NL / 256, 256, 0, stream>>>(x, tables, out);
  }
}